// Round 10
// baseline (97.567 us; speedup 1.0000x reference)
//
#include <hip/hip_runtime.h>
#include <stdint.h>

#define NTOK 16384
#define HID  4096
#define NEXP 64
#define BM   32
#define BK   64
#define NSTEPS 64               // K-steps of 64 floats

typedef _Float16 f16;
typedef f16  f16x8 __attribute__((ext_vector_type(8)));
typedef float f32x4 __attribute__((ext_vector_type(4)));

typedef __attribute__((address_space(3))) uint32_t  lds_u32;
typedef __attribute__((address_space(1))) const uint32_t glb_u32;

// LDS plane layout (R1/R7-proven): [row][64 k] f16, unit u XOR-swizzled with row&7.
__device__ __forceinline__ int swz(int row, int u) {
    return row * 64 + ((u ^ (row & 7)) << 3);
}

// ---- pack w -> gload_lds-ready chunks, pre-swizzled (rule #21) ----
// Per step s (64 k's): 1024 chunks of 16 B. chunk c<512: hi plane, c>=512: lo.
// hi chunk for (expert e, unit u) at c = 8e + (u^(e&7)) -> LDS linear copy
// reproduces the swz() layout exactly.
__global__ __launch_bounds__(256)
void pack_w_kernel(const float* __restrict__ w, f16* __restrict__ wp) {
    int tid = blockIdx.x * 256 + threadIdx.x;   // 32768 threads
    int e  = tid >> 9;                          // 0..63
    int k8 = tid & 511;                         // 0..511
    int k  = k8 << 3;
    const float* src = w + (size_t)e * HID + k;
    float4 v0 = *(const float4*)(src);
    float4 v1 = *(const float4*)(src + 4);
    float sv[8] = {v0.x, v0.y, v0.z, v0.w, v1.x, v1.y, v1.z, v1.w};
    f16x8 hi, lo;
    #pragma unroll
    for (int j = 0; j < 8; ++j) {
        float s = sv[j] * 64.0f;    // exact pow2 scale: lo avoids fp16 subnormals
        f16 h = (f16)s;
        hi[j] = h;
        lo[j] = (f16)(s - (float)h);
    }
    int s = k >> 6;
    int u = (k >> 3) & 7;
    int c = 8 * e + (u ^ (e & 7));
    *(f16x8*)&wp[(size_t)(s * 1024 + c) * 8]       = hi;
    *(f16x8*)&wp[(size_t)(s * 1024 + 512 + c) * 8] = lo;
}

// ---- main: B via gload_lds ring(3), loads issued post-barrier2, 2 blocks/CU ----
__global__ __launch_bounds__(256)
void topk_gate_kernel(const float* __restrict__ x,
                      const f16* __restrict__ wp,
                      float* __restrict__ out) {
    __shared__ __align__(16) f16 Ah[BM * BK];            // 4 KB
    __shared__ __align__(16) f16 Al[BM * BK];            // 4 KB
    __shared__ __align__(16) f16 Bbuf[3][2][NEXP * BK];  // 48 KB ring
    __shared__ float red[2][BM][4];

    const int t    = threadIdx.x;
    const int blk  = blockIdx.x;
    const int lane = t & 63;
    const int wid  = t >> 6;       // 0..3
    const int wm   = wid & 1;      // token half (16 tokens)
    const int wn   = wid >> 1;     // expert half (32 experts)
    const int col  = lane & 15;
    const int grp  = lane >> 4;

    // A staging (R7-proven): 8 threads/row, 8 consecutive floats each
    const int arow_s = t >> 3;             // 0..31
    const int ao     = t & 7;
    const float* asrc = x + ((size_t)blk * BM + arow_s) * HID + ao * 8;
    const int aoff_w = swz(arow_s, ao);

    // B staging: wave wid, insts i=0..3 -> chunk-base cb = wid*4+i (1 KB each)
    #define STAGE(s_, slot_) do {                                               \
        _Pragma("unroll")                                                       \
        for (int i_ = 0; i_ < 4; ++i_) {                                        \
            int cb_ = wid * 4 + i_;                                             \
            __builtin_amdgcn_global_load_lds(                                   \
                (glb_u32*)(const void*)(wp +                                    \
                    ((size_t)(s_) * 1024 + cb_ * 64 + lane) * 8),               \
                (lds_u32*)(void*)((char*)&Bbuf[slot_][0][0] + cb_ * 1024),      \
                16, 0, 0);                                                      \
        }                                                                       \
    } while (0)

    f32x4 acc0 = {0.f, 0.f, 0.f, 0.f};   // experts wn*32 + col
    f32x4 acc1 = {0.f, 0.f, 0.f, 0.f};   // experts wn*32 + 16 + col

    // ---- prologue: B(0)->slot0, B(1)->slot1 in flight; A(0) regs ----
    STAGE(0, 0);
    STAGE(1, 1);
    float4 ca0 = *(const float4*)(asrc);
    float4 ca1 = *(const float4*)(asrc + 4);

    const int arow  = wm * 16 + col;
    const int brow0 = wn * 32 + col;
    const int brow1 = brow0 + 16;

    for (int s = 0; s < NSTEPS; ++s) {
        __syncthreads();   // barrier1: compute(s-1) done; staged loads drained

        // convert A(s): 8 floats -> one f16x8 unit per plane
        {
            float v[8] = {ca0.x, ca0.y, ca0.z, ca0.w, ca1.x, ca1.y, ca1.z, ca1.w};
            f16x8 hi, lo;
            #pragma unroll
            for (int j = 0; j < 8; ++j) {
                f16 h = (f16)v[j];
                hi[j] = h;
                lo[j] = (f16)(v[j] - (float)h);
            }
            *(f16x8*)&Ah[aoff_w] = hi;
            *(f16x8*)&Al[aoff_w] = lo;
        }
        __syncthreads();   // barrier2: A planes visible

        // issue next loads NOW: in flight across the whole compute phase,
        // drained at next barrier1 -> memory pipe stays busy during MFMA.
        if (s + 2 < NSTEPS) STAGE(s + 2, (s + 2) % 3);
        const int sn = (s + 1 < NSTEPS) ? (s + 1) : s;
        float4 na0 = *(const float4*)(asrc + (size_t)sn * BK);
        float4 na1 = *(const float4*)(asrc + (size_t)sn * BK + 4);

        // compute step s from A LDS + B ring slot s%3 (R7-proven fragment math)
        const int slot = s % 3;
        const f16* BhS = &Bbuf[slot][0][0];
        const f16* BlS = &Bbuf[slot][1][0];
        #pragma unroll
        for (int ks = 0; ks < 2; ++ks) {
            int u = ks * 4 + grp;
            f16x8 ah  = *(const f16x8*)&Ah[swz(arow,  u)];
            f16x8 al  = *(const f16x8*)&Al[swz(arow,  u)];
            f16x8 b0h = *(const f16x8*)&BhS[swz(brow0, u)];
            f16x8 b0l = *(const f16x8*)&BlS[swz(brow0, u)];
            f16x8 b1h = *(const f16x8*)&BhS[swz(brow1, u)];
            f16x8 b1l = *(const f16x8*)&BlS[swz(brow1, u)];
            acc0 = __builtin_amdgcn_mfma_f32_16x16x32_f16(ah, b0h, acc0, 0, 0, 0);
            acc0 = __builtin_amdgcn_mfma_f32_16x16x32_f16(ah, b0l, acc0, 0, 0, 0);
            acc0 = __builtin_amdgcn_mfma_f32_16x16x32_f16(al, b0h, acc0, 0, 0, 0);
            acc1 = __builtin_amdgcn_mfma_f32_16x16x32_f16(ah, b1h, acc1, 0, 0, 0);
            acc1 = __builtin_amdgcn_mfma_f32_16x16x32_f16(ah, b1l, acc1, 0, 0, 0);
            acc1 = __builtin_amdgcn_mfma_f32_16x16x32_f16(al, b1h, acc1, 0, 0, 0);
        }

        ca0 = na0; ca1 = na1;
    }

    // ---- epilogue: fused top-2 + softmax (R7-proven verbatim) ----
    #pragma unroll
    for (int r = 0; r < 4; ++r) {
        float va = acc0[r], vb = acc1[r];
        int   ia = wn * 32 + col, ib = ia + 16;
        float v0, v1; int i0, i1;
        if (va >= vb) { v0 = va; i0 = ia; v1 = vb; i1 = ib; }
        else          { v0 = vb; i0 = ib; v1 = va; i1 = ia; }
        #pragma unroll
        for (int m = 1; m <= 8; m <<= 1) {
            float ov0 = __shfl_xor(v0, m, 64);
            int   oi0 = __shfl_xor(i0, m, 64);
            float ov1 = __shfl_xor(v1, m, 64);
            int   oi1 = __shfl_xor(i1, m, 64);
            bool ob = (ov0 > v0) || (ov0 == v0 && oi0 < i0);
            if (ob) {
                bool k2 = (v0 > ov1) || (v0 == ov1 && i0 < oi1);
                v1 = k2 ? v0 : ov1; i1 = k2 ? i0 : oi1;
                v0 = ov0; i0 = oi0;
            } else {
                bool k2 = (ov0 > v1) || (ov0 == v1 && oi0 < i1);
                v1 = k2 ? ov0 : v1; i1 = k2 ? oi0 : i1;
            }
        }
        if (col == 0) {
            int tl = wm * 16 + grp * 4 + r;
            red[wn][tl][0] = v0; red[wn][tl][1] = (float)i0;
            red[wn][tl][2] = v1; red[wn][tl][3] = (float)i1;
        }
    }
    __syncthreads();

    if (t < BM) {
        float v0 = red[0][t][0]; int i0 = (int)red[0][t][1];
        float v1 = red[0][t][2]; int i1 = (int)red[0][t][3];
        float b0 = red[1][t][0]; int bi0 = (int)red[1][t][1];
        float b1 = red[1][t][2]; int bi1 = (int)red[1][t][3];
        bool bb = (b0 > v0) || (b0 == v0 && bi0 < i0);
        if (bb) {
            bool k2 = (v0 > b1) || (v0 == b1 && i0 < bi1);
            float nv1 = k2 ? v0 : b1; int ni1 = k2 ? i0 : bi1;
            v0 = b0; i0 = bi0; v1 = nv1; i1 = ni1;
        } else {
            bool k2 = (b0 > v1) || (b0 == v1 && bi0 < i1);
            v1 = k2 ? b0 : v1; i1 = k2 ? bi0 : i1;
        }
        // softmax over [v0, v1]; logits were scaled x64 via w
        float d  = (v1 - v0) * (1.0f / 64.0f);
        float e  = expf(d);
        float g0 = 1.0f / (1.0f + e);
        float g1 = e / (1.0f + e);

        int tok = blk * BM + t;
        out[(size_t)tok * 2 + 0] = g0;
        out[(size_t)tok * 2 + 1] = g1;
        out[(size_t)NTOK * 2 + (size_t)tok * 2 + 0] = (float)i0;
        out[(size_t)NTOK * 2 + (size_t)tok * 2 + 1] = (float)i1;
    }
}

extern "C" void kernel_launch(void* const* d_in, const int* in_sizes, int n_in,
                              void* d_out, int out_size, void* d_ws, size_t ws_size,
                              hipStream_t stream) {
    const float* x = (const float*)d_in[0];   // [16384, 4096] f32
    const float* w = (const float*)d_in[1];   // [64, 4096] f32
    float* out = (float*)d_out;               // gates [16384,2] then idx-as-f32 [16384,2]
    f16* wp = (f16*)d_ws;                     // 1 MB packed chunks
    (void)in_sizes; (void)n_in; (void)out_size; (void)ws_size;

    pack_w_kernel<<<dim3(128), dim3(256), 0, stream>>>(w, wp);
    topk_gate_kernel<<<dim3(NTOK / BM), dim3(256), 0, stream>>>(x, wp, out);
}